// Round 1
// baseline (1780.380 us; speedup 1.0000x reference)
//
#include <hip/hip_runtime.h>
#include <math.h>

#define N_NODES 50000
#define N_EDGES 500000
#define D 128
#define H 256
#define NE 64
#define TOPK 2
#define NPAIR (N_NODES * TOPK)
#define CAP 3126               // 2 * ceil(100000/64)
#define TILE_R 32
#define TILES_PER_E ((CAP + TILE_R - 1) / TILE_R)   // 98
#define BN_NBLK 128
#define BN_ROWS ((N_NODES + BN_NBLK - 1) / BN_NBLK) // 391

// ---------------- degree count ----------------
__global__ void k_deg(const int* __restrict__ dst, int* __restrict__ deg) {
    int i = blockIdx.x * blockDim.x + threadIdx.x;
    if (i < N_EDGES) atomicAdd(&deg[dst[i]], 1);
}

__global__ void k_invsqrt(const int* __restrict__ deg, float* __restrict__ invs) {
    int i = blockIdx.x * blockDim.x + threadIdx.x;
    if (i < N_NODES) {
        double d = (double)deg[i];
        if (d < 1.0) d = 1.0;
        invs[i] = (float)(1.0 / sqrt(d));
    }
}

// ---------------- edge gather/scatter-add ----------------
// thread = (edge, 4-col group): 32 lanes per edge, float4 each
__global__ __launch_bounds__(256) void k_agg(const float* __restrict__ feats,
                                             const int* __restrict__ src,
                                             const int* __restrict__ dst,
                                             const float* __restrict__ invs,
                                             float* __restrict__ agg) {
    long long gid = (long long)blockIdx.x * blockDim.x + threadIdx.x;
    int e = (int)(gid >> 5);
    int q = (int)(gid & 31);
    if (e >= N_EDGES) return;
    int s = src[e], d = dst[e];
    float norm = invs[s] * invs[d];
    float4 f = ((const float4*)(feats + (size_t)s * D))[q];
    float* a = agg + (size_t)d * D + q * 4;
    atomicAdd(a + 0, f.x * norm);
    atomicAdd(a + 1, f.y * norm);
    atomicAdd(a + 2, f.z * norm);
    atomicAdd(a + 3, f.w * norm);
}

// ---------------- conv GEMM: new_feats = agg @ W_conv + b_conv ----------------
__global__ __launch_bounds__(256) void k_conv(const float* __restrict__ agg,
                                              const float* __restrict__ W,
                                              const float* __restrict__ bias,
                                              float* __restrict__ out) {
    __shared__ float Wl[D * D];        // 64 KB
    __shared__ float xl[TILE_R * D];   // 16 KB
    int r0 = blockIdx.x * TILE_R;
    int rows = min(TILE_R, N_NODES - r0);
    for (int i = threadIdx.x; i < D * D / 4; i += 256)
        ((float4*)Wl)[i] = ((const float4*)W)[i];
    for (int i = threadIdx.x; i < rows * 32; i += 256) {
        int r = i >> 5, q = i & 31;
        ((float4*)(xl + r * D))[q] = ((const float4*)(agg + (size_t)(r0 + r) * D))[q];
    }
    __syncthreads();
    int c = threadIdx.x & 127;
    int half = threadIdx.x >> 7;
    float acc[16];
#pragma unroll
    for (int j = 0; j < 16; j++) acc[j] = 0.f;
    for (int k = 0; k < D; k++) {
        float w = Wl[k * D + c];
#pragma unroll
        for (int j = 0; j < 16; j++) acc[j] += xl[(half + j * 2) * D + k] * w;
    }
    float b = bias[c];
#pragma unroll
    for (int j = 0; j < 16; j++) {
        int r = half + j * 2;
        if (r < rows) out[(size_t)(r0 + r) * D + c] = acc[j] + b;
    }
}

// ---------------- gate: scores (f64 accum), top-2, softmax, dispatch ----------------
__global__ __launch_bounds__(256) void k_gate(const float* __restrict__ nf,
                                              const float* __restrict__ gW,
                                              const float* __restrict__ gb,
                                              int* __restrict__ topi,
                                              float* __restrict__ gwout,
                                              int* __restrict__ cnt,
                                              int* __restrict__ plist) {
    __shared__ float Wl[D * NE];   // 32 KB
    for (int i = threadIdx.x; i < D * NE / 4; i += 256)
        ((float4*)Wl)[i] = ((const float4*)gW)[i];
    __syncthreads();
    int t = blockIdx.x * 4 + (threadIdx.x >> 6);
    if (t >= N_NODES) return;
    int lane = threadIdx.x & 63;
    const float* x = nf + (size_t)t * D;
    double acc = 0.0;
    for (int k = 0; k < D; k++)
        acc += (double)x[k] * (double)Wl[k * NE + lane];
    acc += (double)gb[lane];

    // stable argmax #1 (smaller index wins ties)
    double v1 = acc; int i1 = lane;
#pragma unroll
    for (int off = 32; off; off >>= 1) {
        double ov = __shfl_xor(v1, off);
        int    oi = __shfl_xor(i1, off);
        if (ov > v1 || (ov == v1 && oi < i1)) { v1 = ov; i1 = oi; }
    }
    // argmax #2 excluding i1
    double v2 = (lane == i1) ? -INFINITY : acc; int i2 = lane;
#pragma unroll
    for (int off = 32; off; off >>= 1) {
        double ov = __shfl_xor(v2, off);
        int    oi = __shfl_xor(i2, off);
        if (ov > v2 || (ov == v2 && oi < i2)) { v2 = ov; i2 = oi; }
    }
    if (lane == 0) {
        double e2 = exp(v2 - v1);
        double s = 1.0 + e2;
        topi[2 * t] = i1; topi[2 * t + 1] = i2;
        gwout[2 * t] = (float)(1.0 / s);
        gwout[2 * t + 1] = (float)(e2 / s);
        int p1 = atomicAdd(&cnt[i1], 1);
        if (p1 < CAP) plist[i1 * CAP + p1] = 2 * t;
        int p2 = atomicAdd(&cnt[i2], 1);
        if (p2 < CAP) plist[i2 * CAP + p2] = 2 * t + 1;
    }
}

// ---------------- grouped expert FFN ----------------
__global__ __launch_bounds__(256) void k_moe(const float* __restrict__ nf,
                                             const int* __restrict__ cnt,
                                             const int* __restrict__ plist,
                                             const float* __restrict__ W1,
                                             const float* __restrict__ b1,
                                             const float* __restrict__ W2,
                                             const float* __restrict__ b2,
                                             const float* __restrict__ gwbuf,
                                             float* __restrict__ core) {
    int e = blockIdx.x / TILES_PER_E;
    int tile = blockIdx.x % TILES_PER_E;
    int n = min(cnt[e], CAP);
    int r0 = tile * TILE_R;
    if (r0 >= n) return;
    int rows = min(TILE_R, n - r0);

    __shared__ float xl[TILE_R][D];   // 16 KB
    __shared__ float hl[TILE_R][H];   // 32 KB
    __shared__ int pl[TILE_R];
    if (threadIdx.x < TILE_R)
        pl[threadIdx.x] = (threadIdx.x < rows) ? plist[e * CAP + r0 + threadIdx.x] : 0;
    __syncthreads();
    for (int i = threadIdx.x; i < TILE_R * 32; i += 256) {
        int r = i >> 5, q = i & 31;
        float4 v = make_float4(0.f, 0.f, 0.f, 0.f);
        if (r < rows) {
            int t = pl[r] >> 1;
            v = ((const float4*)(nf + (size_t)t * D))[q];
        }
        ((float4*)xl[r])[q] = v;
    }
    __syncthreads();

    // phase 1: hact = gelu(x @ W1 + b1); each thread owns one h-column
    {
        int hc = threadIdx.x;
        const float* w1p = W1 + (size_t)e * D * H + hc;
        float acc[TILE_R];
#pragma unroll
        for (int j = 0; j < TILE_R; j++) acc[j] = 0.f;
        for (int k = 0; k < D; k++) {
            float w = w1p[(size_t)k * H];
#pragma unroll
            for (int j = 0; j < TILE_R; j++) acc[j] += xl[j][k] * w;
        }
        float bb = b1[e * H + hc];
#pragma unroll
        for (int j = 0; j < TILE_R; j++) {
            float hv = acc[j] + bb;
            hl[j][hc] = 0.5f * hv * (1.0f + erff(hv * 0.70710678118654752f));
        }
    }
    __syncthreads();

    // phase 2: y = hact @ W2 + b2 ; scatter gw*y into core
    {
        int dc = threadIdx.x & 127;
        int half = threadIdx.x >> 7;
        const float* w2p = W2 + (size_t)e * H * D + dc;
        float acc[16];
#pragma unroll
        for (int j = 0; j < 16; j++) acc[j] = 0.f;
        for (int k = 0; k < H; k++) {
            float w = w2p[(size_t)k * D];
#pragma unroll
            for (int j = 0; j < 16; j++) acc[j] += hl[half + j * 2][k] * w;
        }
        float bb = b2[e * D + dc];
#pragma unroll
        for (int j = 0; j < 16; j++) {
            int r = half + j * 2;
            if (r < rows) {
                int p = pl[r];
                int t = p >> 1;
                atomicAdd(&core[(size_t)t * D + dc], gwbuf[p] * (acc[j] + bb));
            }
        }
    }
}

// ---------------- BatchNorm ----------------
__global__ __launch_bounds__(256) void k_bnpart(const float* __restrict__ nf,
                                                const float* __restrict__ core,
                                                double* __restrict__ part) {
    int blk = blockIdx.x;
    int col = threadIdx.x & 127;
    int half = threadIdx.x >> 7;
    int r0 = blk * BN_ROWS;
    int r1 = min(r0 + BN_ROWS, N_NODES);
    double s = 0.0, ss = 0.0;
    for (int r = r0 + half; r < r1; r += 2) {
        float v32 = nf[(size_t)r * D + col] + core[(size_t)r * D + col];
        double v = (double)v32;
        s += v; ss += v * v;
    }
    __shared__ double sh[2][256];
    sh[0][threadIdx.x] = s; sh[1][threadIdx.x] = ss;
    __syncthreads();
    if (threadIdx.x < 128) {
        part[(size_t)blk * 256 + col]       = sh[0][col] + sh[0][col + 128];
        part[(size_t)blk * 256 + 128 + col] = sh[1][col] + sh[1][col + 128];
    }
}

__global__ void k_bnstats(const double* __restrict__ part,
                          const float* __restrict__ gamma,
                          float* __restrict__ stats) {
    int col = threadIdx.x;   // 128 threads
    double s = 0.0, ss = 0.0;
    for (int b = 0; b < BN_NBLK; b++) {
        s  += part[(size_t)b * 256 + col];
        ss += part[(size_t)b * 256 + 128 + col];
    }
    double mean = s / (double)N_NODES;
    double var = ss / (double)N_NODES - mean * mean;
    stats[col] = (float)mean;
    stats[128 + col] = gamma[col] * (float)(1.0 / sqrt(var + 1e-5));
}

__global__ __launch_bounds__(256) void k_bnapply(const float* __restrict__ core,
                                                 const float* __restrict__ stats,
                                                 const float* __restrict__ beta,
                                                 float* __restrict__ out) {
    int i = blockIdx.x * blockDim.x + threadIdx.x;   // float4 index
    if (i >= N_NODES * (D / 4)) return;
    int c0 = (i * 4) & 127;
    float4 v = ((float4*)out)[i];
    float4 c = ((const float4*)core)[i];
    float4 r;
    r.x = (v.x + c.x - stats[c0 + 0]) * stats[128 + c0 + 0] + beta[c0 + 0];
    r.y = (v.y + c.y - stats[c0 + 1]) * stats[128 + c0 + 1] + beta[c0 + 1];
    r.z = (v.z + c.z - stats[c0 + 2]) * stats[128 + c0 + 2] + beta[c0 + 2];
    r.w = (v.w + c.w - stats[c0 + 3]) * stats[128 + c0 + 3] + beta[c0 + 3];
    ((float4*)out)[i] = r;
}

// ---------------- launch ----------------
extern "C" void kernel_launch(void* const* d_in, const int* in_sizes, int n_in,
                              void* d_out, int out_size, void* d_ws, size_t ws_size,
                              hipStream_t stream) {
    const float* feats   = (const float*)d_in[0];
    const int*   esrc    = (const int*)d_in[1];
    const int*   edst    = (const int*)d_in[2];
    const float* W_conv  = (const float*)d_in[3];
    const float* b_conv  = (const float*)d_in[4];
    const float* gate_W  = (const float*)d_in[5];
    const float* gate_b  = (const float*)d_in[6];
    const float* W1      = (const float*)d_in[7];
    const float* b1      = (const float*)d_in[8];
    const float* W2      = (const float*)d_in[9];
    const float* b2      = (const float*)d_in[10];
    const float* bn_g    = (const float*)d_in[11];
    const float* bn_b    = (const float*)d_in[12];
    float* out = (float*)d_out;   // doubles as new_feats storage

    char* ws = (char*)d_ws;
    size_t off = 0;
    float*  agg   = (float*)(ws + off); off += (size_t)N_NODES * D * 4;   // 25.6 MB
    float*  core  = (float*)(ws + off); off += (size_t)N_NODES * D * 4;   // 25.6 MB
    int*    deg   = (int*)  (ws + off); off += (size_t)N_NODES * 4;
    int*    cnt   = (int*)  (ws + off); off += 256;
    size_t zero_bytes = off;                                              // agg+core+deg+cnt
    float*  invs  = (float*)(ws + off); off += (size_t)N_NODES * 4;
    int*    topi  = (int*)  (ws + off); off += (size_t)NPAIR * 4;
    float*  gwbuf = (float*)(ws + off); off += (size_t)NPAIR * 4;
    int*    plist = (int*)  (ws + off); off += (size_t)NE * CAP * 4;
    double* part  = (double*)(ws + off); off += (size_t)BN_NBLK * 256 * 8;
    float*  stats = (float*)(ws + off); off += 1024;
    (void)ws_size; (void)in_sizes; (void)n_in; (void)out_size; (void)topi;

    hipMemsetAsync(d_ws, 0, zero_bytes, stream);

    k_deg<<<(N_EDGES + 255) / 256, 256, 0, stream>>>(edst, deg);
    k_invsqrt<<<(N_NODES + 255) / 256, 256, 0, stream>>>(deg, invs);
    k_agg<<<(N_EDGES * 32) / 256, 256, 0, stream>>>(feats, esrc, edst, invs, agg);
    k_conv<<<(N_NODES + TILE_R - 1) / TILE_R, 256, 0, stream>>>(agg, W_conv, b_conv, out);
    k_gate<<<(N_NODES + 3) / 4, 256, 0, stream>>>(out, gate_W, gate_b, topi, gwbuf, cnt, plist);
    k_moe<<<NE * TILES_PER_E, 256, 0, stream>>>(out, cnt, plist, W1, b1, W2, b2, gwbuf, core);
    k_bnpart<<<BN_NBLK, 256, 0, stream>>>(out, core, part);
    k_bnstats<<<1, 128, 0, stream>>>(part, bn_g, stats);
    k_bnapply<<<(N_NODES * (D / 4) + 255) / 256, 256, 0, stream>>>(core, stats, bn_b, out);
}

// Round 2
// 1157.039 us; speedup vs baseline: 1.5387x; 1.5387x over previous
//
#include <hip/hip_runtime.h>
#include <math.h>

#define N_NODES 50000
#define N_EDGES 500000
#define D 128
#define H 256
#define NE 64
#define TOPK 2
#define NPAIR (N_NODES * TOPK)
#define CAP 3126               // 2 * ceil(100000/64)
#define TILE_R 32
#define TILES_PER_E ((CAP + TILE_R - 1) / TILE_R)   // 98
#define BN_NBLK 128
#define BN_ROWS ((N_NODES + BN_NBLK - 1) / BN_NBLK) // 391

// ---------------- degree count ----------------
__global__ void k_deg(const int* __restrict__ dst, int* __restrict__ deg) {
    int i = blockIdx.x * blockDim.x + threadIdx.x;
    if (i < N_EDGES) atomicAdd(&deg[dst[i]], 1);
}

__global__ void k_invsqrt(const int* __restrict__ deg, float* __restrict__ invs) {
    int i = blockIdx.x * blockDim.x + threadIdx.x;
    if (i < N_NODES) {
        double d = (double)deg[i];
        if (d < 1.0) d = 1.0;
        invs[i] = (float)(1.0 / sqrt(d));
    }
}

// ---------------- exclusive scan of deg -> rowptr ----------------
__global__ __launch_bounds__(1024) void k_scan(const int* __restrict__ deg,
                                               int* __restrict__ rowptr) {
    __shared__ int sh[1024];
    int t = threadIdx.x;
    const int chunk = (N_NODES + 1023) / 1024;   // 49
    int lo = t * chunk;
    int hi = min(lo + chunk, N_NODES);
    int s = 0;
    for (int i = lo; i < hi; i++) s += deg[i];
    sh[t] = s;
    __syncthreads();
    for (int off = 1; off < 1024; off <<= 1) {
        int v = (t >= off) ? sh[t - off] : 0;
        __syncthreads();
        sh[t] += v;
        __syncthreads();
    }
    int run = (t == 0) ? 0 : sh[t - 1];
    for (int i = lo; i < hi; i++) { rowptr[i] = run; run += deg[i]; }
    if (t == 1023) rowptr[N_NODES] = run;
}

// ---------------- scatter edges into CSR ----------------
__global__ void k_scatter(const int* __restrict__ src, const int* __restrict__ dst,
                          const int* __restrict__ rowptr, int* __restrict__ cursor,
                          int* __restrict__ csr) {
    int e = blockIdx.x * blockDim.x + threadIdx.x;
    if (e >= N_EDGES) return;
    int d = dst[e];
    int pos = atomicAdd(&cursor[d], 1);
    csr[rowptr[d] + pos] = src[e];
}

// ---------------- per-node gather (wave per node, f64 accumulate) ----------------
__global__ __launch_bounds__(256) void k_gather(const float* __restrict__ feats,
                                                const int* __restrict__ rowptr,
                                                const int* __restrict__ csr,
                                                const float* __restrict__ invs,
                                                float* __restrict__ agg) {
    int node = blockIdx.x * 4 + (threadIdx.x >> 6);
    if (node >= N_NODES) return;
    int lane = threadIdx.x & 63;
    int beg = rowptr[node], end = rowptr[node + 1];
    float wd = invs[node];
    double ax = 0.0, ay = 0.0;
    for (int i = beg; i < end; i++) {
        int s = csr[i];
        float norm = invs[s] * wd;               // f32, matches reference per-edge value
        float2 f = ((const float2*)(feats + (size_t)s * D))[lane];
        ax += (double)(norm * f.x);              // order-independent f64 sum
        ay += (double)(norm * f.y);
    }
    ((float2*)(agg + (size_t)node * D))[lane] = make_float2((float)ax, (float)ay);
}

// ---------------- conv GEMM: new_feats = agg @ W_conv + b_conv ----------------
__global__ __launch_bounds__(256) void k_conv(const float* __restrict__ agg,
                                              const float* __restrict__ W,
                                              const float* __restrict__ bias,
                                              float* __restrict__ out) {
    __shared__ float Wl[D * D];        // 64 KB
    __shared__ float xl[TILE_R * D];   // 16 KB
    int r0 = blockIdx.x * TILE_R;
    int rows = min(TILE_R, N_NODES - r0);
    for (int i = threadIdx.x; i < D * D / 4; i += 256)
        ((float4*)Wl)[i] = ((const float4*)W)[i];
    for (int i = threadIdx.x; i < rows * 32; i += 256) {
        int r = i >> 5, q = i & 31;
        ((float4*)(xl + r * D))[q] = ((const float4*)(agg + (size_t)(r0 + r) * D))[q];
    }
    __syncthreads();
    int c = threadIdx.x & 127;
    int half = threadIdx.x >> 7;
    float acc[16];
#pragma unroll
    for (int j = 0; j < 16; j++) acc[j] = 0.f;
    for (int k = 0; k < D; k++) {
        float w = Wl[k * D + c];
#pragma unroll
        for (int j = 0; j < 16; j++) acc[j] += xl[(half + j * 2) * D + k] * w;
    }
    float b = bias[c];
#pragma unroll
    for (int j = 0; j < 16; j++) {
        int r = half + j * 2;
        if (r < rows) out[(size_t)(r0 + r) * D + c] = acc[j] + b;
    }
}

// ---------------- gate: scores (f64 accum), top-2, softmax, dispatch ----------------
__global__ __launch_bounds__(256) void k_gate(const float* __restrict__ nf,
                                              const float* __restrict__ gW,
                                              const float* __restrict__ gb,
                                              float* __restrict__ gwout,
                                              int* __restrict__ cnt,
                                              int* __restrict__ plist) {
    __shared__ float Wl[D * NE];   // 32 KB
    for (int i = threadIdx.x; i < D * NE / 4; i += 256)
        ((float4*)Wl)[i] = ((const float4*)gW)[i];
    __syncthreads();
    int t = blockIdx.x * 4 + (threadIdx.x >> 6);
    if (t >= N_NODES) return;
    int lane = threadIdx.x & 63;
    const float* x = nf + (size_t)t * D;
    double acc = 0.0;
    for (int k = 0; k < D; k++)
        acc += (double)x[k] * (double)Wl[k * NE + lane];
    acc += (double)gb[lane];

    double v1 = acc; int i1 = lane;
#pragma unroll
    for (int off = 32; off; off >>= 1) {
        double ov = __shfl_xor(v1, off);
        int    oi = __shfl_xor(i1, off);
        if (ov > v1 || (ov == v1 && oi < i1)) { v1 = ov; i1 = oi; }
    }
    double v2 = (lane == i1) ? -INFINITY : acc; int i2 = lane;
#pragma unroll
    for (int off = 32; off; off >>= 1) {
        double ov = __shfl_xor(v2, off);
        int    oi = __shfl_xor(i2, off);
        if (ov > v2 || (ov == v2 && oi < i2)) { v2 = ov; i2 = oi; }
    }
    if (lane == 0) {
        double e2 = exp(v2 - v1);
        double s = 1.0 + e2;
        gwout[2 * t] = (float)(1.0 / s);
        gwout[2 * t + 1] = (float)(e2 / s);
        int p1 = atomicAdd(&cnt[i1], 1);
        if (p1 < CAP) plist[i1 * CAP + p1] = 2 * t;
        int p2 = atomicAdd(&cnt[i2], 1);
        if (p2 < CAP) plist[i2 * CAP + p2] = 2 * t + 1;
    }
}

// ---------------- grouped expert FFN (writes per-pair rows, no atomics) ----------------
__global__ __launch_bounds__(256) void k_moe(const float* __restrict__ nf,
                                             const int* __restrict__ cnt,
                                             const int* __restrict__ plist,
                                             const float* __restrict__ W1,
                                             const float* __restrict__ b1,
                                             const float* __restrict__ W2,
                                             const float* __restrict__ b2,
                                             const float* __restrict__ gwbuf,
                                             float* __restrict__ ybuf) {
    int e = blockIdx.x / TILES_PER_E;
    int tile = blockIdx.x % TILES_PER_E;
    int n = min(cnt[e], CAP);
    int r0 = tile * TILE_R;
    if (r0 >= n) return;
    int rows = min(TILE_R, n - r0);

    __shared__ float xl[TILE_R][D];   // 16 KB
    __shared__ float hl[TILE_R][H];   // 32 KB
    __shared__ int pl[TILE_R];
    if (threadIdx.x < TILE_R)
        pl[threadIdx.x] = (threadIdx.x < rows) ? plist[e * CAP + r0 + threadIdx.x] : 0;
    __syncthreads();
    for (int i = threadIdx.x; i < TILE_R * 32; i += 256) {
        int r = i >> 5, q = i & 31;
        float4 v = make_float4(0.f, 0.f, 0.f, 0.f);
        if (r < rows) {
            int t = pl[r] >> 1;
            v = ((const float4*)(nf + (size_t)t * D))[q];
        }
        ((float4*)xl[r])[q] = v;
    }
    __syncthreads();

    // phase 1: hact = gelu(x @ W1 + b1)
    {
        int hc = threadIdx.x;
        const float* w1p = W1 + (size_t)e * D * H + hc;
        float acc[TILE_R];
#pragma unroll
        for (int j = 0; j < TILE_R; j++) acc[j] = 0.f;
        for (int k = 0; k < D; k++) {
            float w = w1p[(size_t)k * H];
#pragma unroll
            for (int j = 0; j < TILE_R; j++) acc[j] += xl[j][k] * w;
        }
        float bb = b1[e * H + hc];
#pragma unroll
        for (int j = 0; j < TILE_R; j++) {
            float hv = acc[j] + bb;
            hl[j][hc] = 0.5f * hv * (1.0f + erff(hv * 0.70710678118654752f));
        }
    }
    __syncthreads();

    // phase 2: y = hact @ W2 + b2 ; store gw*y to pair row
    {
        int dc = threadIdx.x & 127;
        int half = threadIdx.x >> 7;
        const float* w2p = W2 + (size_t)e * H * D + dc;
        float acc[16];
#pragma unroll
        for (int j = 0; j < 16; j++) acc[j] = 0.f;
        for (int k = 0; k < H; k++) {
            float w = w2p[(size_t)k * D];
#pragma unroll
            for (int j = 0; j < 16; j++) acc[j] += hl[half + j * 2][k] * w;
        }
        float bb = b2[e * D + dc];
#pragma unroll
        for (int j = 0; j < 16; j++) {
            int r = half + j * 2;
            if (r < rows) {
                int p = pl[r];
                ybuf[(size_t)p * D + dc] = gwbuf[p] * (acc[j] + bb);
            }
        }
    }
}

// ---------------- BatchNorm ----------------
__global__ __launch_bounds__(256) void k_bnpart(const float* __restrict__ nf,
                                                const float* __restrict__ ybuf,
                                                double* __restrict__ part) {
    int blk = blockIdx.x;
    int col = threadIdx.x & 127;
    int half = threadIdx.x >> 7;
    int r0 = blk * BN_ROWS;
    int r1 = min(r0 + BN_ROWS, N_NODES);
    double s = 0.0, ss = 0.0;
    for (int r = r0 + half; r < r1; r += 2) {
        float v32 = nf[(size_t)r * D + col]
                  + ybuf[(size_t)(2 * r) * D + col]
                  + ybuf[(size_t)(2 * r + 1) * D + col];
        double v = (double)v32;
        s += v; ss += v * v;
    }
    __shared__ double sh[2][256];
    sh[0][threadIdx.x] = s; sh[1][threadIdx.x] = ss;
    __syncthreads();
    if (threadIdx.x < 128) {
        part[(size_t)blk * 256 + col]       = sh[0][col] + sh[0][col + 128];
        part[(size_t)blk * 256 + 128 + col] = sh[1][col] + sh[1][col + 128];
    }
}

__global__ void k_bnstats(const double* __restrict__ part,
                          const float* __restrict__ gamma,
                          float* __restrict__ stats) {
    int col = threadIdx.x;   // 128 threads
    double s = 0.0, ss = 0.0;
    for (int b = 0; b < BN_NBLK; b++) {
        s  += part[(size_t)b * 256 + col];
        ss += part[(size_t)b * 256 + 128 + col];
    }
    double mean = s / (double)N_NODES;
    double var = ss / (double)N_NODES - mean * mean;
    stats[col] = (float)mean;
    stats[128 + col] = gamma[col] * (float)(1.0 / sqrt(var + 1e-5));
}

__global__ __launch_bounds__(256) void k_bnapply(const float* __restrict__ ybuf,
                                                 const float* __restrict__ stats,
                                                 const float* __restrict__ beta,
                                                 float* __restrict__ out) {
    int i = blockIdx.x * blockDim.x + threadIdx.x;   // float4 index
    if (i >= N_NODES * (D / 4)) return;
    int t = i >> 5;
    int q = i & 31;
    int c0 = q * 4;
    float4 v  = ((float4*)out)[i];
    float4 y0 = ((const float4*)(ybuf + (size_t)(2 * t) * D))[q];
    float4 y1 = ((const float4*)(ybuf + (size_t)(2 * t + 1) * D))[q];
    float4 r;
    r.x = (v.x + y0.x + y1.x - stats[c0 + 0]) * stats[128 + c0 + 0] + beta[c0 + 0];
    r.y = (v.y + y0.y + y1.y - stats[c0 + 1]) * stats[128 + c0 + 1] + beta[c0 + 1];
    r.z = (v.z + y0.z + y1.z - stats[c0 + 2]) * stats[128 + c0 + 2] + beta[c0 + 2];
    r.w = (v.w + y0.w + y1.w - stats[c0 + 3]) * stats[128 + c0 + 3] + beta[c0 + 3];
    ((float4*)out)[i] = r;
}

// ---------------- launch ----------------
extern "C" void kernel_launch(void* const* d_in, const int* in_sizes, int n_in,
                              void* d_out, int out_size, void* d_ws, size_t ws_size,
                              hipStream_t stream) {
    const float* feats   = (const float*)d_in[0];
    const int*   esrc    = (const int*)d_in[1];
    const int*   edst    = (const int*)d_in[2];
    const float* W_conv  = (const float*)d_in[3];
    const float* b_conv  = (const float*)d_in[4];
    const float* gate_W  = (const float*)d_in[5];
    const float* gate_b  = (const float*)d_in[6];
    const float* W1      = (const float*)d_in[7];
    const float* b1      = (const float*)d_in[8];
    const float* W2      = (const float*)d_in[9];
    const float* b2      = (const float*)d_in[10];
    const float* bn_g    = (const float*)d_in[11];
    const float* bn_b    = (const float*)d_in[12];
    float* out = (float*)d_out;   // doubles as new_feats storage

    char* ws = (char*)d_ws;
    size_t off = 0;
    auto rup = [](size_t x) { return (x + 255) & ~(size_t)255; };
    int*    deg    = (int*)   (ws + off); off += rup((size_t)N_NODES * 4);
    int*    cursor = (int*)   (ws + off); off += rup((size_t)N_NODES * 4);
    int*    cnt    = (int*)   (ws + off); off += 256;
    size_t zero_bytes = off;                 // deg + cursor + cnt only (~400 KB)
    float*  invs   = (float*) (ws + off); off += rup((size_t)N_NODES * 4);
    int*    rowptr = (int*)   (ws + off); off += rup((size_t)(N_NODES + 1) * 4);
    int*    csr    = (int*)   (ws + off); off += rup((size_t)N_EDGES * 4);
    float*  gwbuf  = (float*) (ws + off); off += rup((size_t)NPAIR * 4);
    int*    plist  = (int*)   (ws + off); off += rup((size_t)NE * CAP * 4);
    double* part   = (double*)(ws + off); off += rup((size_t)BN_NBLK * 256 * 8);
    float*  stats  = (float*) (ws + off); off += 1024;
    float*  ybuf   = (float*) (ws + off); off += rup((size_t)NPAIR * D * 4); // 51.2 MB
    float*  agg    = ybuf;   // lifetime-disjoint alias (agg dead before k_moe writes ybuf)
    (void)ws_size; (void)in_sizes; (void)n_in; (void)out_size;

    hipMemsetAsync(d_ws, 0, zero_bytes, stream);

    k_deg<<<(N_EDGES + 255) / 256, 256, 0, stream>>>(edst, deg);
    k_invsqrt<<<(N_NODES + 255) / 256, 256, 0, stream>>>(deg, invs);
    k_scan<<<1, 1024, 0, stream>>>(deg, rowptr);
    k_scatter<<<(N_EDGES + 255) / 256, 256, 0, stream>>>(esrc, edst, rowptr, cursor, csr);
    k_gather<<<(N_NODES + 3) / 4, 256, 0, stream>>>(feats, rowptr, csr, invs, agg);
    k_conv<<<(N_NODES + TILE_R - 1) / TILE_R, 256, 0, stream>>>(agg, W_conv, b_conv, out);
    k_gate<<<(N_NODES + 3) / 4, 256, 0, stream>>>(out, gate_W, gate_b, gwbuf, cnt, plist);
    k_moe<<<NE * TILES_PER_E, 256, 0, stream>>>(out, cnt, plist, W1, b1, W2, b2, gwbuf, ybuf);
    k_bnpart<<<BN_NBLK, 256, 0, stream>>>(out, ybuf, part);
    k_bnstats<<<1, 128, 0, stream>>>(part, bn_g, stats);
    k_bnapply<<<(N_NODES * (D / 4) + 255) / 256, 256, 0, stream>>>(ybuf, stats, bn_b, out);
}